// Round 5
// baseline (28.076 us; speedup 1.0000x reference)
//
#include <hip/hip_runtime.h>

// Problem constants (match reference setup_inputs)
constexpr int B = 8;
constexpr int L = 4096;
constexpr int D = 1024;
constexpr int S = 128;
constexpr int P = L - 64;   // 4032

// Native vector type: __builtin_nontemporal_load/store accepts ext_vector,
// not HIP_vector_type<float,4>.
typedef float f32x4 __attribute__((ext_vector_type(4)));

// 2048 blocks: one per (batch, sentence, D-half). 128 threads each; each
// thread owns one f32x4 column of its half. subword2sents is sorted per
// batch, so sentence s spans [lower_bound(s), lower_bound(s+1)).
//
// Tail-balance: the 24 KB LDS allocation caps residency at 6 blocks/CU
// (144/160 KB) -> 1536 resident + 512 queued, giving the HW workgroup
// scheduler a queue to dynamically rebalance the Binomial-distributed
// sentence lengths (previously all blocks were co-resident -> static
// schedule -> ~2 us end-phase underutilization).
constexpr int LDS_PAD_INTS = (24 * 1024) / 4;

__global__ __launch_bounds__(128)
void word2sent_pool_kernel(const float* __restrict__ words_emb,
                           const int* __restrict__ bounds,
                           const int* __restrict__ s2s,
                           float* __restrict__ out)
{
    const int blk  = blockIdx.x;     // b*256 + s*2 + half
    const int b    = blk >> 8;
    const int rem  = blk & 255;
    const int s    = rem >> 1;
    const int half = rem & 1;
    const int tid  = threadIdx.x;
    const int wave = tid >> 6;       // 0..1
    const int lane = tid & 63;

    const int* __restrict__ row = s2s + b * P;

    // sh[0]=lower_bound(s), sh[1]=lower_bound(s+1); rest is occupancy cap.
    __shared__ int sh[LDS_PAD_INTS];

    {
        const int v = s + wave;      // wave 0 -> s, wave 1 -> s+1
        // Round 1: probe row[lane*63], lane = 0..63 (max 3969 < P).
        // c = #probes < v  ->  lower_bound in ((c-1)*63, c*63].
        const int p1 = row[lane * 63];
        const unsigned long long m1 = __ballot(p1 < v);
        const int c = __popcll(m1);
        const int base = (c == 0) ? 0 : (c - 1) * 63 + 1;
        // Round 2: probe the 63-wide window exactly.
        const int pos = base + lane;
        int pred2 = 0;
        if (lane < 63 && pos < P) pred2 = (row[pos] < v) ? 1 : 0;
        const unsigned long long m2 = __ballot(pred2);
        if (lane == 0) sh[wave] = base + __popcll(m2);
    }
    __syncthreads();

    const int start = sh[0];
    const int cnt   = sh[1] - start;

    const int q0 = bounds[b * 2];    // passage start (dynamic slice offset)

    const f32x4* __restrict__ base4 = reinterpret_cast<const f32x4*>(
        words_emb + ((size_t)b * L + (size_t)q0 + (size_t)start) * D);

    const int d4 = half * 128 + tid; // 0..255 -> f32x4 column of D
    const int rowstride = D / 4;     // 256 f32x4 per token row

    f32x4 acc = (f32x4)(0.f);
    #pragma unroll 8
    for (int t = 0; t < cnt; ++t) {
        // read-once stream: keep it out of L2 (s2s probes stay cached)
        f32x4 v = __builtin_nontemporal_load(&base4[(size_t)t * rowstride + d4]);
        acc += v;
    }

    const float inv = 1.0f / (float)(cnt > 0 ? cnt : 1);
    f32x4 r = acc * inv;

    f32x4* __restrict__ out4 = reinterpret_cast<f32x4*>(out);
    __builtin_nontemporal_store(r, &out4[(size_t)(b * S + s) * rowstride + d4]);
}

extern "C" void kernel_launch(void* const* d_in, const int* in_sizes, int n_in,
                              void* d_out, int out_size, void* d_ws, size_t ws_size,
                              hipStream_t stream) {
    const float* words_emb = (const float*)d_in[0];   // [B, L, D] f32
    const int* bounds      = (const int*)d_in[1];     // [B, 2] i32
    const int* s2s         = (const int*)d_in[2];     // [B, P] i32 (sorted per row)
    float* out             = (float*)d_out;           // [B, S, D] f32

    dim3 grid(B * S * 2);
    dim3 block(128);
    word2sent_pool_kernel<<<grid, block, 0, stream>>>(words_emb, bounds, s2s, out);
}